// Round 1
// baseline (969.003 us; speedup 1.0000x reference)
//
#include <hip/hip_runtime.h>
#include <math.h>

#define T_LEN 65536
#define CHUNK 128
#define NCHUNK 512

// ws layout
#define CONS_BYTES ((size_t)T_LEN * 192 * 4)              // 48 MB: [t][as|aw|bp][64]
#define BUFA_OFF   CONS_BYTES
#define BUFA_BYTES ((size_t)NCHUNK * 4096 * 4)            // 8 MB
#define BUFB_OFF   (BUFA_OFF + BUFA_BYTES)
#define BUFB_BYTES ((size_t)(NCHUNK / 2) * 4096 * 4)      // 4 MB
#define WS_NEEDED  (BUFB_OFF + BUFB_BYTES)

// ---------------- Kernel 1: gather + exp precompute ----------------
// cons[t*192 +   b] = exp(ac_lp)*exp(start_lp)   (as)
// cons[t*192 +64+b] = exp(ac_lp)*exp(cont_lp)    (aw)
// cons[t*192+128+b] = exp(stop_lp)               (bp)
__global__ __launch_bounds__(256) void k_prep(const float* __restrict__ alp,
                                              const float* __restrict__ stp,
                                              const float* __restrict__ srt,
                                              const int* __restrict__ act,
                                              float* __restrict__ cons) {
    int gid = blockIdx.x * 256 + threadIdx.x;
    int t = gid >> 6;
    int b = gid & 63;
    if (t >= T_LEN) return;
    int a = act[t];
    float ac = __expf(alp[(size_t)t * 2048 + b * 32 + a]);
    float sp = __expf(srt[t * 64 + b]);
    float2 st2 = ((const float2*)stp)[t * 64 + b];
    float bp = __expf(st2.x);  // stop
    float cp = __expf(st2.y);  // continue
    size_t o = (size_t)t * 192 + b;
    cons[o]       = ac * sp;
    cons[o + 64]  = ac * cp;
    cons[o + 128] = bp;
}

// ---------------- Kernel 2: per-chunk transfer matrix ----------------
// thread (col = tid&63, g = tid>>6) owns rows [16g,16g+16) of column col.
#define K2_LOAD(BUF, II) do {                                                  \
    int ic_ = (II); if (ic_ > T_LEN - 1) ic_ = T_LEN - 1;                      \
    const float4* p_ = (const float4*)(cons + (size_t)ic_ * 192 + r0);         \
    const float4* q_ = (const float4*)(cons + (size_t)ic_ * 192 + 64 + r0);    \
    const float4* s_ = (const float4*)(cons + (size_t)ic_ * 192 + 128 + r0);   \
    _Pragma("unroll") for (int u = 0; u < 4; ++u) as##BUF[u] = p_[u];          \
    _Pragma("unroll") for (int u = 0; u < 4; ++u) aw##BUF[u] = q_[u];          \
    _Pragma("unroll") for (int u = 0; u < 4; ++u) bp##BUF[u] = s_[u];          \
} while (0)

#define K2_STEP(BUF, JJ) do {                                                  \
    const int i_ = ibase + (JJ);                                               \
    if (i_ < T_LEN) {                                                          \
        float sp_ = 0.f;                                                       \
        _Pragma("unroll")                                                      \
        for (int u = 0; u < 4; ++u) {                                          \
            sp_ += bp##BUF[u].x * m[4*u+0] + bp##BUF[u].y * m[4*u+1]           \
                 + bp##BUF[u].z * m[4*u+2] + bp##BUF[u].w * m[4*u+3];          \
        }                                                                      \
        part[g][col] = sp_;                                                    \
        __syncthreads();                                                       \
        float sig = part[0][col] + part[1][col] + part[2][col] + part[3][col]; \
        __syncthreads();                                                       \
        _Pragma("unroll")                                                      \
        for (int u = 0; u < 4; ++u) {                                          \
            m[4*u+0] = fmaf(aw##BUF[u].x, m[4*u+0], as##BUF[u].x * sig);       \
            m[4*u+1] = fmaf(aw##BUF[u].y, m[4*u+1], as##BUF[u].y * sig);       \
            m[4*u+2] = fmaf(aw##BUF[u].z, m[4*u+2], as##BUF[u].z * sig);       \
            m[4*u+3] = fmaf(aw##BUF[u].w, m[4*u+3], as##BUF[u].w * sig);       \
        }                                                                      \
        if (((JJ) & 3) == 3) {                                                 \
            float mxv = 0.f;                                                   \
            _Pragma("unroll")                                                  \
            for (int k = 0; k < 16; ++k) mxv = fmaxf(mxv, m[k]);               \
            part[g][col] = mxv;                                                \
            __syncthreads();                                                   \
            float cmax = fmaxf(fmaxf(part[0][col], part[1][col]),              \
                               fmaxf(part[2][col], part[3][col]));             \
            __syncthreads();                                                   \
            if (cmax > 0.f) {                                                  \
                float inv = 1.0f / cmax;                                       \
                _Pragma("unroll")                                              \
                for (int k = 0; k < 16; ++k) m[k] *= inv;                      \
                lsc += __logf(cmax);                                           \
            } else { lsc = -1e30f; }                                           \
        }                                                                      \
    }                                                                          \
} while (0)

__global__ __launch_bounds__(256) void k_chunk(const float* __restrict__ cons,
                                               float* __restrict__ mats) {
    const int tid = threadIdx.x;
    const int col = tid & 63;
    const int g = tid >> 6;
    const int r0 = __builtin_amdgcn_readfirstlane(g << 4);
    __shared__ float part[4][64];
    float m[16];
#pragma unroll
    for (int k = 0; k < 16; ++k) m[k] = (r0 + k == col) ? 1.0f : 0.0f;
    float lsc = 0.0f;
    const int chunk = blockIdx.x;
    const int ibase = 1 + chunk * CHUNK;

    float4 as0[4], aw0[4], bp0[4], as1[4], aw1[4], bp1[4];
    K2_LOAD(0, ibase);
#pragma unroll 1
    for (int j = 0; j < CHUNK; j += 2) {
        K2_LOAD(1, ibase + j + 1);
        K2_STEP(0, j);
        K2_LOAD(0, ibase + j + 2);
        K2_STEP(1, j + 1);
    }

    float* out = mats + (size_t)chunk * 4096;
#pragma unroll
    for (int k = 0; k < 16; ++k) {
        float v = (m[k] > 0.f) ? (__logf(m[k]) + lsc) : -1e30f;
        out[(r0 + k) * 64 + col] = fmaxf(v, -1e30f);
    }
}

// ---------------- Kernel 3: log-space pairwise matrix combine ----------------
// out[b] = Later(2b+1) o Earlier(2b):  out[r][c] = lse_k( L[r][k] + E[k][c] )
__global__ __launch_bounds__(256) void k_combine(const float* __restrict__ in,
                                                 float* __restrict__ out) {
    __shared__ float Es[4096];
    __shared__ float Ls[4096];
    const int tid = threadIdx.x;
    const int bid = blockIdx.x;
    const float* Ein = in + (size_t)(2 * bid) * 4096;
    const float* Lin = in + (size_t)(2 * bid + 1) * 4096;
    for (int idx = tid; idx < 1024; idx += 256) {
        ((float4*)Es)[idx] = ((const float4*)Ein)[idx];
        ((float4*)Ls)[idx] = ((const float4*)Lin)[idx];
    }
    __syncthreads();
    const int col = tid & 63;
    const int r0 = (tid >> 6) << 4;
    float mx[16], sm[16];
#pragma unroll
    for (int u = 0; u < 16; ++u) { mx[u] = -3.4e38f; sm[u] = 0.f; }
    // pass 1: exact max per output
#pragma unroll 1
    for (int kt = 0; kt < 4; ++kt) {
        float ec[16];
#pragma unroll
        for (int q = 0; q < 16; ++q) ec[q] = Es[(kt * 16 + q) * 64 + col];
#pragma unroll
        for (int u = 0; u < 16; ++u) {
            const float4* lr = (const float4*)(Ls + (r0 + u) * 64 + kt * 16);
#pragma unroll
            for (int q4 = 0; q4 < 4; ++q4) {
                float4 l4 = lr[q4];
                float t0 = fmaxf(l4.x + ec[4*q4+0], l4.y + ec[4*q4+1]);
                float t1 = fmaxf(l4.z + ec[4*q4+2], l4.w + ec[4*q4+3]);
                mx[u] = fmaxf(mx[u], fmaxf(t0, t1));
            }
        }
    }
    // pass 2: shifted exp-sum
#pragma unroll 1
    for (int kt = 0; kt < 4; ++kt) {
        float ec[16];
#pragma unroll
        for (int q = 0; q < 16; ++q) ec[q] = Es[(kt * 16 + q) * 64 + col];
#pragma unroll
        for (int u = 0; u < 16; ++u) {
            const float4* lr = (const float4*)(Ls + (r0 + u) * 64 + kt * 16);
#pragma unroll
            for (int q4 = 0; q4 < 4; ++q4) {
                float4 l4 = lr[q4];
                sm[u] += __expf(l4.x + ec[4*q4+0] - mx[u]);
                sm[u] += __expf(l4.y + ec[4*q4+1] - mx[u]);
                sm[u] += __expf(l4.z + ec[4*q4+2] - mx[u]);
                sm[u] += __expf(l4.w + ec[4*q4+3] - mx[u]);
            }
        }
    }
    float* o = out + (size_t)bid * 4096;
#pragma unroll
    for (int u = 0; u < 16; ++u) {
        float v = mx[u] + __logf(sm[u]);
        o[(r0 + u) * 64 + col] = fmaxf(v, -1e30f);
    }
}

// ---------------- Kernel 4: finalize (f0 -> 32 matvecs -> answer) ----------------
__global__ __launch_bounds__(256) void k_final(const float* __restrict__ mats,
                                               const float* __restrict__ alp,
                                               const float* __restrict__ stp,
                                               const float* __restrict__ srt,
                                               const int* __restrict__ act,
                                               float* __restrict__ out) {
    __shared__ float f[64];
    __shared__ float matl[64 * 65];
    __shared__ float part[4][64];
    const int tid = threadIdx.x;
    const int r = tid & 63;
    const int g = tid >> 6;
    if (tid < 64) {
        int a0 = act[0];
        f[tid] = srt[tid] + alp[tid * 32 + a0];
    }
    __syncthreads();
#pragma unroll 1
    for (int mi = 0; mi < 32; ++mi) {
        const float* M = mats + (size_t)mi * 4096;
        for (int idx = tid; idx < 1024; idx += 256) {
            float4 v = ((const float4*)M)[idx];
            int rr = idx >> 4;
            int c0 = (idx & 15) * 4;
            matl[rr * 65 + c0 + 0] = v.x;
            matl[rr * 65 + c0 + 1] = v.y;
            matl[rr * 65 + c0 + 2] = v.z;
            matl[rr * 65 + c0 + 3] = v.w;
        }
        __syncthreads();
        float bm = -3.4e38f;
#pragma unroll
        for (int q = 0; q < 16; ++q) {
            int c = g * 16 + q;
            bm = fmaxf(bm, matl[r * 65 + c] + f[c]);
        }
        part[g][r] = bm;
        __syncthreads();
        float mxr = fmaxf(fmaxf(part[0][r], part[1][r]),
                          fmaxf(part[2][r], part[3][r]));
        __syncthreads();
        float s = 0.f;
#pragma unroll
        for (int q = 0; q < 16; ++q) {
            int c = g * 16 + q;
            s += __expf(matl[r * 65 + c] + f[c] - mxr);
        }
        part[g][r] = s;
        __syncthreads();
        if (g == 0) {
            float st = part[0][r] + part[1][r] + part[2][r] + part[3][r];
            f[r] = fmaxf(mxr + __logf(st), -1e30f);
        }
        __syncthreads();
    }
    if (tid < 64) {
        part[0][tid] = f[tid] + stp[(size_t)T_LEN * 128 + 2 * tid];
    }
    __syncthreads();
    if (tid == 0) {
        float mxx = -3.4e38f;
        for (int c = 0; c < 64; ++c) mxx = fmaxf(mxx, part[0][c]);
        float s = 0.f;
        for (int c = 0; c < 64; ++c) s += __expf(part[0][c] - mxx);
        out[0] = -(mxx + __logf(s));
    }
}

__global__ void k_wsfail(float* out, float v) { out[0] = v; }

extern "C" void kernel_launch(void* const* d_in, const int* in_sizes, int n_in,
                              void* d_out, int out_size, void* d_ws, size_t ws_size,
                              hipStream_t stream) {
    const float* alp = (const float*)d_in[0];   // action_logps (T+1, 64, 32)
    const float* stp = (const float*)d_in[1];   // stop_logps   (T+1, 64, 2)
    const float* srt = (const float*)d_in[2];   // start_logps  (T+1, 64)
    const int* act = (const int*)d_in[3];       // actions      (T,)
    float* outp = (float*)d_out;

    if (ws_size < WS_NEEDED) {  // diagnostic sentinel: absmax will echo ws_size
        k_wsfail<<<1, 1, 0, stream>>>(outp, (float)ws_size);
        return;
    }
    char* ws = (char*)d_ws;
    float* cons = (float*)ws;
    float* bufA = (float*)(ws + BUFA_OFF);
    float* bufB = (float*)(ws + BUFB_OFF);

    k_prep<<<dim3(16384), dim3(256), 0, stream>>>(alp, stp, srt, act, cons);
    k_chunk<<<dim3(NCHUNK), dim3(256), 0, stream>>>(cons, bufA);
    k_combine<<<dim3(256), dim3(256), 0, stream>>>(bufA, bufB);  // 512 -> 256
    k_combine<<<dim3(128), dim3(256), 0, stream>>>(bufB, bufA);  // 256 -> 128
    k_combine<<<dim3(64),  dim3(256), 0, stream>>>(bufA, bufB);  // 128 -> 64
    k_combine<<<dim3(32),  dim3(256), 0, stream>>>(bufB, bufA);  //  64 -> 32
    k_final<<<dim3(1), dim3(256), 0, stream>>>(bufA, alp, stp, srt, act, outp);
}

// Round 2
// 815.563 us; speedup vs baseline: 1.1881x; 1.1881x over previous
//
#include <hip/hip_runtime.h>
#include <math.h>

#define T_LEN 65536
#define CHUNK 128
#define NCHUNK 512
#define GSTEP 8
#define NGROUP (CHUNK / GSTEP)   // 16

// ws layout: bufA (512 mats), bufB (256 mats)
#define BUFA_BYTES ((size_t)NCHUNK * 4096 * 4)            // 8 MB
#define BUFB_BYTES ((size_t)(NCHUNK / 2) * 4096 * 4)      // 4 MB
#define WS_NEEDED  (BUFA_BYTES + BUFB_BYTES)

// ---------------- Kernel 1: fused gather/exp + per-chunk transfer matrix ----------------
// Linear-space recurrence per column c:
//   sigma_c = sum_r bp[r]*M[r][c];  M[r][c] <- aw[r]*M[r][c] + as[r]*sigma_c
// with as = exp(ac+start), aw = exp(ac+cont), bp = exp(stop).
// Thread (col = tid&63, wv = tid>>6) owns rows [16*wv, 16*wv+16) of column col.
// Step data staged global->reg->exp->LDS, double-buffered in groups of 8 steps.
__global__ __launch_bounds__(256) void k_fchunk(const float* __restrict__ alp,
                                                const float* __restrict__ stp,
                                                const float* __restrict__ srt,
                                                const int* __restrict__ act,
                                                float* __restrict__ mats) {
    const int tid = threadIdx.x;
    const int col = tid & 63;
    const int wv  = tid >> 6;        // 0..3
    const int r0  = wv << 4;
    __shared__ float part[4][64];
    __shared__ float sAS[2][GSTEP][64];
    __shared__ float sAW[2][GSTEP][64];
    __shared__ float sBP[2][GSTEP][64];

    float m[16];
#pragma unroll
    for (int k = 0; k < 16; ++k) m[k] = (r0 + k == col) ? 1.0f : 0.0f;
    float lsc = 0.0f;
    const int chunk = blockIdx.x;
    const int ibase = 1 + chunk * CHUNK;

    // staging regs: each thread covers steps (wv) and (wv+4) of a group, state b=col
    float ga[2], gs[2];
    float2 gp[2];
    int pad[2];

    auto load_group = [&](int gg) {
#pragma unroll
        for (int h = 0; h < 2; ++h) {
            int i = ibase + gg * GSTEP + wv + 4 * h;   // step index, <= T_LEN
            pad[h] = (i >= T_LEN);                     // only last step of last chunk
            int ia = pad[h] ? T_LEN : i;               // rows 0..T_LEN valid (T+1 rows)
            int aidx = act[pad[h] ? (T_LEN - 1) : i];  // act has T entries
            ga[h] = alp[(size_t)ia * 2048 + col * 32 + aidx];
            gs[h] = srt[ia * 64 + col];
            gp[h] = ((const float2*)stp)[ia * 64 + col];
        }
    };
    auto write_group = [&](int buf) {
#pragma unroll
        for (int h = 0; h < 2; ++h) {
            int s = wv + 4 * h;
            float as_v = pad[h] ? 0.0f : __expf(ga[h] + gs[h]);
            float aw_v = pad[h] ? 1.0f : __expf(ga[h] + gp[h].y);
            float bp_v = pad[h] ? 0.0f : __expf(gp[h].x);
            sAS[buf][s][col] = as_v;
            sAW[buf][s][col] = aw_v;
            sBP[buf][s][col] = bp_v;
        }
    };

    load_group(0);
    write_group(0);
    __syncthreads();
    int cur = 0;

#pragma unroll 1
    for (int gg = 0; gg < NGROUP; ++gg) {
        if (gg + 1 < NGROUP) load_group(gg + 1);   // prefetch next group (global->reg)
#pragma unroll
        for (int j = 0; j < GSTEP; ++j) {
            float4 asv[4], awv[4], bpv[4];
            const float4* pAS = (const float4*)(&sAS[cur][j][r0]);
            const float4* pAW = (const float4*)(&sAW[cur][j][r0]);
            const float4* pBP = (const float4*)(&sBP[cur][j][r0]);
#pragma unroll
            for (int u = 0; u < 4; ++u) asv[u] = pAS[u];
#pragma unroll
            for (int u = 0; u < 4; ++u) awv[u] = pAW[u];
#pragma unroll
            for (int u = 0; u < 4; ++u) bpv[u] = pBP[u];
            // sigma partial over this wave's 16 rows
            float sp_ = 0.f;
#pragma unroll
            for (int u = 0; u < 4; ++u) {
                sp_ += bpv[u].x * m[4*u+0] + bpv[u].y * m[4*u+1]
                     + bpv[u].z * m[4*u+2] + bpv[u].w * m[4*u+3];
            }
            part[wv][col] = sp_;
            __syncthreads();
            float sig = part[0][col] + part[1][col] + part[2][col] + part[3][col];
            __syncthreads();
#pragma unroll
            for (int u = 0; u < 4; ++u) {
                m[4*u+0] = fmaf(awv[u].x, m[4*u+0], asv[u].x * sig);
                m[4*u+1] = fmaf(awv[u].y, m[4*u+1], asv[u].y * sig);
                m[4*u+2] = fmaf(awv[u].z, m[4*u+2], asv[u].z * sig);
                m[4*u+3] = fmaf(awv[u].w, m[4*u+3], asv[u].w * sig);
            }
            int jabs = gg * GSTEP + j;
            if ((jabs & 3) == 3) {   // per-column rescale every 4 steps
                float mxv = 0.f;
#pragma unroll
                for (int k = 0; k < 16; ++k) mxv = fmaxf(mxv, m[k]);
                part[wv][col] = mxv;
                __syncthreads();
                float cmax = fmaxf(fmaxf(part[0][col], part[1][col]),
                                   fmaxf(part[2][col], part[3][col]));
                __syncthreads();
                if (cmax > 0.f) {
                    float inv = 1.0f / cmax;
#pragma unroll
                    for (int k = 0; k < 16; ++k) m[k] *= inv;
                    lsc += __logf(cmax);
                } else { lsc = -1e30f; }
            }
        }
        if (gg + 1 < NGROUP) write_group(cur ^ 1);  // exp + stage into idle buffer
        __syncthreads();
        cur ^= 1;
    }

    float* out = mats + (size_t)chunk * 4096;
#pragma unroll
    for (int k = 0; k < 16; ++k) {
        float v = (m[k] > 0.f) ? (__logf(m[k]) + lsc) : -1e30f;
        out[(r0 + k) * 64 + col] = fmaxf(v, -1e30f);
    }
}

// ---------------- Kernel 2: log-space pairwise matrix combine ----------------
// out[b] = Later(2b+1) o Earlier(2b):  out[r][c] = lse_k( L[r][k] + E[k][c] )
__global__ __launch_bounds__(256) void k_combine(const float* __restrict__ in,
                                                 float* __restrict__ out) {
    __shared__ float Es[4096];
    __shared__ float Ls[4096];
    const int tid = threadIdx.x;
    const int bid = blockIdx.x;
    const float* Ein = in + (size_t)(2 * bid) * 4096;
    const float* Lin = in + (size_t)(2 * bid + 1) * 4096;
    for (int idx = tid; idx < 1024; idx += 256) {
        ((float4*)Es)[idx] = ((const float4*)Ein)[idx];
        ((float4*)Ls)[idx] = ((const float4*)Lin)[idx];
    }
    __syncthreads();
    const int col = tid & 63;
    const int r0 = (tid >> 6) << 4;
    float mx[16], sm[16];
#pragma unroll
    for (int u = 0; u < 16; ++u) { mx[u] = -3.4e38f; sm[u] = 0.f; }
    // pass 1: exact max per output
#pragma unroll 1
    for (int kt = 0; kt < 4; ++kt) {
        float ec[16];
#pragma unroll
        for (int q = 0; q < 16; ++q) ec[q] = Es[(kt * 16 + q) * 64 + col];
#pragma unroll
        for (int u = 0; u < 16; ++u) {
            const float4* lr = (const float4*)(Ls + (r0 + u) * 64 + kt * 16);
#pragma unroll
            for (int q4 = 0; q4 < 4; ++q4) {
                float4 l4 = lr[q4];
                float t0 = fmaxf(l4.x + ec[4*q4+0], l4.y + ec[4*q4+1]);
                float t1 = fmaxf(l4.z + ec[4*q4+2], l4.w + ec[4*q4+3]);
                mx[u] = fmaxf(mx[u], fmaxf(t0, t1));
            }
        }
    }
    // pass 2: shifted exp-sum
#pragma unroll 1
    for (int kt = 0; kt < 4; ++kt) {
        float ec[16];
#pragma unroll
        for (int q = 0; q < 16; ++q) ec[q] = Es[(kt * 16 + q) * 64 + col];
#pragma unroll
        for (int u = 0; u < 16; ++u) {
            const float4* lr = (const float4*)(Ls + (r0 + u) * 64 + kt * 16);
#pragma unroll
            for (int q4 = 0; q4 < 4; ++q4) {
                float4 l4 = lr[q4];
                sm[u] += __expf(l4.x + ec[4*q4+0] - mx[u]);
                sm[u] += __expf(l4.y + ec[4*q4+1] - mx[u]);
                sm[u] += __expf(l4.z + ec[4*q4+2] - mx[u]);
                sm[u] += __expf(l4.w + ec[4*q4+3] - mx[u]);
            }
        }
    }
    float* o = out + (size_t)bid * 4096;
#pragma unroll
    for (int u = 0; u < 16; ++u) {
        float v = mx[u] + __logf(sm[u]);
        o[(r0 + u) * 64 + col] = fmaxf(v, -1e30f);
    }
}

// ---------------- Kernel 3: finalize (f0 -> 32 matvecs -> answer), prefetched ----------------
__global__ __launch_bounds__(256) void k_final(const float* __restrict__ mats,
                                               const float* __restrict__ alp,
                                               const float* __restrict__ stp,
                                               const float* __restrict__ srt,
                                               const int* __restrict__ act,
                                               float* __restrict__ out) {
    __shared__ float f[64];
    __shared__ float matl[64 * 65];
    __shared__ float part[4][64];
    const int tid = threadIdx.x;
    const int r = tid & 63;
    const int g = tid >> 6;
    if (tid < 64) {
        int a0 = act[0];
        f[tid] = srt[tid] + alp[tid * 32 + a0];
    }
    float4 pre[4];
#pragma unroll
    for (int u = 0; u < 4; ++u) pre[u] = ((const float4*)mats)[tid + 256 * u];
    auto write_m = [&]() {
#pragma unroll
        for (int u = 0; u < 4; ++u) {
            int idx = tid + 256 * u;       // 0..1023
            int rr = idx >> 4;
            int c0 = (idx & 15) * 4;
            matl[rr * 65 + c0 + 0] = pre[u].x;
            matl[rr * 65 + c0 + 1] = pre[u].y;
            matl[rr * 65 + c0 + 2] = pre[u].z;
            matl[rr * 65 + c0 + 3] = pre[u].w;
        }
    };
    write_m();
    __syncthreads();
#pragma unroll 1
    for (int mi = 0; mi < 32; ++mi) {
        if (mi + 1 < 32) {   // prefetch next matrix while computing this one
            const float* M = mats + (size_t)(mi + 1) * 4096;
#pragma unroll
            for (int u = 0; u < 4; ++u) pre[u] = ((const float4*)M)[tid + 256 * u];
        }
        float bm = -3.4e38f;
#pragma unroll
        for (int q = 0; q < 16; ++q) {
            int c = g * 16 + q;
            bm = fmaxf(bm, matl[r * 65 + c] + f[c]);
        }
        part[g][r] = bm;
        __syncthreads();
        float mxr = fmaxf(fmaxf(part[0][r], part[1][r]),
                          fmaxf(part[2][r], part[3][r]));
        __syncthreads();
        float s = 0.f;
#pragma unroll
        for (int q = 0; q < 16; ++q) {
            int c = g * 16 + q;
            s += __expf(matl[r * 65 + c] + f[c] - mxr);
        }
        part[g][r] = s;
        __syncthreads();      // all matl reads for this mi are done
        if (mi + 1 < 32) write_m();
        if (g == 0) {
            float st = part[0][r] + part[1][r] + part[2][r] + part[3][r];
            f[r] = fmaxf(mxr + __logf(st), -1e30f);
        }
        __syncthreads();
    }
    if (tid < 64) {
        part[0][tid] = f[tid] + stp[(size_t)T_LEN * 128 + 2 * tid];
    }
    __syncthreads();
    if (tid == 0) {
        float mxx = -3.4e38f;
        for (int c = 0; c < 64; ++c) mxx = fmaxf(mxx, part[0][c]);
        float s = 0.f;
        for (int c = 0; c < 64; ++c) s += __expf(part[0][c] - mxx);
        out[0] = -(mxx + __logf(s));
    }
}

__global__ void k_wsfail(float* out, float v) { out[0] = v; }

extern "C" void kernel_launch(void* const* d_in, const int* in_sizes, int n_in,
                              void* d_out, int out_size, void* d_ws, size_t ws_size,
                              hipStream_t stream) {
    const float* alp = (const float*)d_in[0];   // action_logps (T+1, 64, 32)
    const float* stp = (const float*)d_in[1];   // stop_logps   (T+1, 64, 2)
    const float* srt = (const float*)d_in[2];   // start_logps  (T+1, 64)
    const int* act = (const int*)d_in[3];       // actions      (T,)
    float* outp = (float*)d_out;

    if (ws_size < WS_NEEDED) {  // diagnostic sentinel: absmax will echo ws_size
        k_wsfail<<<1, 1, 0, stream>>>(outp, (float)ws_size);
        return;
    }
    char* ws = (char*)d_ws;
    float* bufA = (float*)ws;
    float* bufB = (float*)(ws + BUFA_BYTES);

    k_fchunk<<<dim3(NCHUNK), dim3(256), 0, stream>>>(alp, stp, srt, act, bufA);
    k_combine<<<dim3(256), dim3(256), 0, stream>>>(bufA, bufB);  // 512 -> 256
    k_combine<<<dim3(128), dim3(256), 0, stream>>>(bufB, bufA);  // 256 -> 128
    k_combine<<<dim3(64),  dim3(256), 0, stream>>>(bufA, bufB);  // 128 -> 64
    k_combine<<<dim3(32),  dim3(256), 0, stream>>>(bufB, bufA);  //  64 -> 32
    k_final<<<dim3(1), dim3(256), 0, stream>>>(bufA, alp, stp, srt, act, outp);
}